// Round 1
// baseline (1154.646 us; speedup 1.0000x reference)
//
#include <hip/hip_runtime.h>
#include <cstdint>
#include <cstddef>

#define K5 5
#define BNEPS 1e-5f

// Fused: (optional 2x linear upsample of input) -> reflect-pad dilated conv1d
// -> (optional eval-BN + ReLU | bias) . Output length LOUT == conv input length.
// Input staging resolves upsample+reflect into LDS tile sx[CI_CHUNK][XT].
// Weights staged as sw[(ci*5+k)*COUT + co] for vectorized reads.
template<int CIN, int COUT, int DIL, int LOUT, bool UP_IN, int THREADS_CO,
         int TT_T, int CI_CHUNK, bool HAS_BN>
__global__ __launch_bounds__(256) void conv_bn_up_ker(
    const float* __restrict__ in, const float* __restrict__ wgt,
    const float* __restrict__ gg, const float* __restrict__ bb,
    const float* __restrict__ mm, const float* __restrict__ vv,
    float* __restrict__ out)
{
    constexpr int THREADS = 256;
    constexpr int P = 2 * DIL;                       // ((K-1)*d+1)//2 == 2d
    constexpr int THREADS_T = THREADS / THREADS_CO;
    constexpr int CO_T = COUT / THREADS_CO;
    constexpr int T_TILE = THREADS_T * TT_T;
    constexpr int XT = T_TILE + 4 * DIL;             // staged input extent
    constexpr int W = TT_T + 4 * DIL;                // per-thread window
    constexpr int LIN_BASE = UP_IN ? (LOUT / 2) : LOUT;
    constexpr int LIN = LOUT;                        // conv input length

    __shared__ float sx[CI_CHUNK * XT];
    __shared__ float sw[CI_CHUNK * K5 * COUT];

    const int n = blockIdx.x;
    const int t0 = blockIdx.y * T_TILE;
    const int tid = threadIdx.x;
    const int co_grp = tid / THREADS_T;
    const int t_grp = tid % THREADS_T;
    const int co_base = co_grp * CO_T;

    float acc[CO_T * TT_T];
#pragma unroll
    for (int i = 0; i < CO_T * TT_T; ++i) acc[i] = 0.f;

    for (int ci0 = 0; ci0 < CIN; ci0 += CI_CHUNK) {
        if (ci0 != 0) __syncthreads();
        // stage weights chunk
        for (int idx = tid; idx < CI_CHUNK * K5 * COUT; idx += THREADS) {
            int co = idx % COUT;
            int r = idx / COUT;          // ci*5 + k
            int ci = r / K5, k = r - ci * K5;
            sw[idx] = wgt[((size_t)co * CIN + (ci0 + ci)) * K5 + k];
        }
        // stage input chunk (reflect + optional upsample resolved here)
        for (int idx = tid; idx < CI_CHUNK * XT; idx += THREADS) {
            int ci = idx / XT;
            int j = idx - ci * XT;
            int u = t0 - P + j;
            u = (u < 0) ? -u : u;
            u = (u >= LIN) ? (2 * (LIN - 1) - u) : u;
            const float* base = in + ((size_t)n * CIN + (ci0 + ci)) * LIN_BASE;
            float val;
            if constexpr (UP_IN) {
                int i = u >> 1;
                if (u & 1) {   // 0.75*b[i] + 0.25*b[min(i+1,L-1)]
                    int i1 = (i + 1 < LIN_BASE) ? (i + 1) : (LIN_BASE - 1);
                    val = 0.75f * base[i] + 0.25f * base[i1];
                } else {       // i==0 ? b[0] : 0.25*b[i-1]+0.75*b[i]
                    val = (i == 0) ? base[0] : (0.25f * base[i - 1] + 0.75f * base[i]);
                }
            } else {
                val = base[u];
            }
            sx[idx] = val;
        }
        __syncthreads();

#pragma unroll 1
        for (int ci = 0; ci < CI_CHUNK; ++ci) {
            float xw[W];
            const float4* xp = (const float4*)(sx + ci * XT + t_grp * TT_T);
#pragma unroll
            for (int j = 0; j < W / 4; ++j) {
                float4 v = xp[j];
                xw[4 * j + 0] = v.x; xw[4 * j + 1] = v.y;
                xw[4 * j + 2] = v.z; xw[4 * j + 3] = v.w;
            }
#pragma unroll
            for (int k = 0; k < K5; ++k) {
                float wv[CO_T];
                if constexpr ((CO_T & 3) == 0) {
                    const float4* wp = (const float4*)(sw + (ci * K5 + k) * COUT + co_base);
#pragma unroll
                    for (int j = 0; j < CO_T / 4; ++j) {
                        float4 v = wp[j];
                        wv[4 * j + 0] = v.x; wv[4 * j + 1] = v.y;
                        wv[4 * j + 2] = v.z; wv[4 * j + 3] = v.w;
                    }
                } else {
#pragma unroll
                    for (int a = 0; a < CO_T; ++a)
                        wv[a] = sw[(ci * K5 + k) * COUT + co_base + a];
                }
#pragma unroll
                for (int a = 0; a < CO_T; ++a)
#pragma unroll
                    for (int b = 0; b < TT_T; ++b)
                        acc[a * TT_T + b] = fmaf(wv[a], xw[b + k * DIL], acc[a * TT_T + b]);
            }
        }
    }

#pragma unroll
    for (int a = 0; a < CO_T; ++a) {
        int co = co_base + a;
        float scale, shift;
        if constexpr (HAS_BN) {
            float inv = gg[co] / sqrtf(vv[co] + BNEPS);
            scale = inv;
            shift = bb[co] - mm[co] * inv;
        } else {
            scale = 1.f;
            shift = bb[co];   // bias (b_out) passed via bb
        }
        float* op = out + ((size_t)n * COUT + co) * LOUT + t0 + t_grp * TT_T;
#pragma unroll
        for (int q = 0; q < TT_T / 4; ++q) {
            float r0 = acc[a * TT_T + 4 * q + 0] * scale + shift;
            float r1 = acc[a * TT_T + 4 * q + 1] * scale + shift;
            float r2 = acc[a * TT_T + 4 * q + 2] * scale + shift;
            float r3 = acc[a * TT_T + 4 * q + 3] * scale + shift;
            if constexpr (HAS_BN) {
                r0 = fmaxf(r0, 0.f); r1 = fmaxf(r1, 0.f);
                r2 = fmaxf(r2, 0.f); r3 = fmaxf(r3, 0.f);
            }
            float4 v; v.x = r0; v.y = r1; v.z = r2; v.w = r3;
            ((float4*)op)[q] = v;
        }
    }
}

// Final: 2x upsample of h4 (256,3,16384) -> out[bt,c,t,st] (32,3,32768,8),
// fused log-softmax(3) cross-entropy partial sums + per-(bt,st) nonzero flags.
__global__ __launch_bounds__(256) void up_loss_ker(
    const float* __restrict__ h4, const float* __restrict__ targets,
    float* __restrict__ out, float* __restrict__ loss_sum, int* __restrict__ flags)
{
    constexpr int L = 16384, LO = 32768;
    const int bt = blockIdx.x;
    const int t0 = blockIdx.y * 256;
    const int tid = threadIdx.x;
    const int st = tid & 7, tloc = tid >> 3;
    const int i0 = t0 >> 1;

    __shared__ float sh[3 * 8 * 132];   // rows (c,st), cols: base idx i0-1+j (clamped)
    __shared__ int snz[8];
    __shared__ float swv[4];

    for (int idx = tid; idx < 3 * 8 * 132; idx += 256) {
        int row = idx / 132;
        int j = idx - row * 132;
        int c = row >> 3, s = row & 7;
        int bi = i0 - 1 + j;
        bi = bi < 0 ? 0 : (bi > L - 1 ? L - 1 : bi);
        int n = bt * 8 + s;
        sh[idx] = h4[((size_t)n * 3 + c) * L + bi];
    }
    if (tid < 8) snz[tid] = 0;
    __syncthreads();

    float lsum = 0.f;
    int nz = 0;
#pragma unroll
    for (int r = 0; r < 8; ++r) {
        int t = t0 + r * 32 + tloc;
        float o[3], tg[3];
        int i = t >> 1;
        int li = i - i0 + 1;
#pragma unroll
        for (int c = 0; c < 3; ++c) {
            const float* row = sh + (c * 8 + st) * 132;
            float v;
            if (t & 1) v = 0.75f * row[li] + 0.25f * row[li + 1];
            else       v = 0.25f * row[li - 1] + 0.75f * row[li];
            o[c] = v;
            size_t oidx = (((size_t)bt * 3 + c) * LO + t) * 8 + st;
            out[oidx] = v;
            tg[c] = targets[oidx];
        }
        float mx = fmaxf(o[0], fmaxf(o[1], o[2]));
        float e0 = __expf(o[0] - mx), e1 = __expf(o[1] - mx), e2 = __expf(o[2] - mx);
        float lse = mx + __logf(e0 + e1 + e2);
        lsum += tg[0] * (lse - o[0]) + tg[1] * (lse - o[1]) + tg[2] * (lse - o[2]);
        nz |= (tg[0] != 0.f) | (tg[1] != 0.f) | (tg[2] != 0.f);
    }
    if (nz) snz[st] = 1;

#pragma unroll
    for (int off = 32; off > 0; off >>= 1) lsum += __shfl_down(lsum, off, 64);
    if ((tid & 63) == 0) swv[tid >> 6] = lsum;
    __syncthreads();
    if (tid == 0) atomicAdd(loss_sum, swv[0] + swv[1] + swv[2] + swv[3]);
    if (tid < 8 && snz[tid]) atomicOr(&flags[bt * 8 + tid], 1);
}

__global__ __launch_bounds__(256) void finalize_ker(
    const int* __restrict__ flags, const float* __restrict__ loss_sum,
    float* __restrict__ out_loss)
{
    __shared__ int s[256];
    s[threadIdx.x] = flags[threadIdx.x] ? 1 : 0;
    __syncthreads();
    for (int off = 128; off > 0; off >>= 1) {
        if (threadIdx.x < off) s[threadIdx.x] += s[threadIdx.x + off];
        __syncthreads();
    }
    if (threadIdx.x == 0) out_loss[0] = loss_sum[0] / ((float)s[0] * 32768.0f);
}

extern "C" void kernel_launch(void* const* d_in, const int* in_sizes, int n_in,
                              void* d_out, int out_size, void* d_ws, size_t ws_size,
                              hipStream_t stream)
{
    // dict order: x, targets, then per layer i: w,g,b,m,v ; then w_out, b_out
    const float* x  = (const float*)d_in[0];
    const float* tg = (const float*)d_in[1];
    const float* w0 = (const float*)d_in[2];
    const float* g0 = (const float*)d_in[3];
    const float* b0 = (const float*)d_in[4];
    const float* m0 = (const float*)d_in[5];
    const float* v0 = (const float*)d_in[6];
    const float* w1 = (const float*)d_in[7];
    const float* g1 = (const float*)d_in[8];
    const float* b1 = (const float*)d_in[9];
    const float* m1 = (const float*)d_in[10];
    const float* v1 = (const float*)d_in[11];
    const float* w2 = (const float*)d_in[12];
    const float* g2 = (const float*)d_in[13];
    const float* b2 = (const float*)d_in[14];
    const float* m2 = (const float*)d_in[15];
    const float* v2 = (const float*)d_in[16];
    const float* w3 = (const float*)d_in[17];
    const float* g3 = (const float*)d_in[18];
    const float* b3 = (const float*)d_in[19];
    const float* m3 = (const float*)d_in[20];
    const float* v3 = (const float*)d_in[21];
    const float* w_out = (const float*)d_in[22];
    const float* b_out = (const float*)d_in[23];
    float* outp = (float*)d_out;

    char* ws = (char*)d_ws;
    int* flags = (int*)ws;                         // 256 ints
    float* loss_sum = (float*)(ws + 1024);         // 1 float
    const size_t BUFN = (size_t)16777216;          // floats per ping-pong buffer
    float* bufA = (float*)(ws + 4096);
    float* bufB = (ws_size >= (size_t)4096 + 2 * BUFN * 4)
                      ? (bufA + BUFN)
                      : (float*)d_out;             // d_out as scratch fallback

    hipMemsetAsync(d_ws, 0, 4096, stream);

    // h0 = relu(bn(conv(x)))            (256, 64, 1024)
    conv_bn_up_ker<128, 64, 1, 1024, false, 8, 8, 16, true>
        <<<dim3(256, 4), 256, 0, stream>>>(x, w0, g0, b0, m0, v0, bufA);
    // h1 = relu(bn(conv(up2(h0))))      (256, 32, 2048)
    conv_bn_up_ker<64, 32, 2, 2048, true, 4, 8, 16, true>
        <<<dim3(256, 4), 256, 0, stream>>>(bufA, w1, g1, b1, m1, v1, bufB);
    // h2                                 (256, 16, 4096)
    conv_bn_up_ker<32, 16, 4, 4096, true, 2, 8, 8, true>
        <<<dim3(256, 4), 256, 0, stream>>>(bufB, w2, g2, b2, m2, v2, bufA);
    // h3                                 (256, 8, 8192)
    conv_bn_up_ker<16, 8, 8, 8192, true, 1, 8, 4, true>
        <<<dim3(256, 4), 256, 0, stream>>>(bufA, w3, g3, b3, m3, v3, bufB);
    // h4 = conv(up2(h3)) + b_out         (256, 3, 16384)
    conv_bn_up_ker<8, 3, 16, 16384, true, 1, 8, 4, false>
        <<<dim3(256, 8), 256, 0, stream>>>(bufB, w_out, b_out, b_out, b_out, b_out, bufA);
    // out = up2(h4) transposed; fused loss partials
    up_loss_ker<<<dim3(32, 128), 256, 0, stream>>>(bufA, tg, outp, loss_sum, flags);
    finalize_ker<<<1, 256, 0, stream>>>(flags, loss_sum, outp + (size_t)(out_size - 1));
}

// Round 2
// 677.131 us; speedup vs baseline: 1.7052x; 1.7052x over previous
//
#include <hip/hip_runtime.h>
#include <hip/hip_bf16.h>
#include <cstdint>
#include <cstddef>

#define K5 5
#define BNEPS 1e-5f

typedef __attribute__((ext_vector_type(8))) short short8v;
typedef __attribute__((ext_vector_type(4))) float float4v;

// ---------------- weight prep: fp32 [co][ci][tap] -> bf16 [co][tap*CIN+ci] ----
template<int CIN, int COUT>
__global__ __launch_bounds__(256) void wprep_ker(const float* __restrict__ w,
                                                 short* __restrict__ wb) {
    constexpr int K = CIN * K5;
    int idx = blockIdx.x * 256 + threadIdx.x;
    if (idx >= COUT * K) return;
    int co = idx / K, k = idx - co * K;
    int tap = k / CIN, ci = k - tap * CIN;
    __hip_bfloat16 h = __float2bfloat16(w[((size_t)co * CIN + ci) * K5 + tap]);
    wb[idx] = *(short*)&h;
}

// ---------------- MFMA conv: (opt up2) -> reflect-pad dilated conv -> BN+ReLU -
// GEMM: D[co][t] = W[co][k] * X[k][t], k = tap*CIN+ci (tap-major).
// X staged in LDS as sx[t][ci] bf16 (+8 pad, conflict-free), staged once,
// no barrier in K-loop. Weights from pre-transposed bf16 global (L1/L2 hot).
template<int CIN, int COUT, int DIL, int LOUT, bool UP_IN>
__global__ __launch_bounds__(256) void conv_mfma_ker(
    const float* __restrict__ in, const short* __restrict__ wb,
    const float* __restrict__ gg, const float* __restrict__ bb,
    const float* __restrict__ mm, const float* __restrict__ vv,
    float* __restrict__ out)
{
    constexpr int T_TILE = 256;
    constexpr int P = 2 * DIL;                 // ((K-1)*d+1)//2 == 2d
    constexpr int XT = T_TILE + 4 * DIL;
    constexpr int ROWW = CIN + 8;              // bf16 row stride (pad: bank spread)
    constexpr int K = CIN * K5;
    constexpr int COT = COUT / 16;             // co tiles (m)
    constexpr int TN = 4;                      // t tiles per wave (n)
    constexpr int LIN = LOUT;
    constexpr int LIN_BASE = UP_IN ? (LOUT / 2) : LOUT;
    constexpr int CI32 = CIN / 32;

    __shared__ short sx[XT * ROWW];
    __shared__ float ssc[COUT], ssh[COUT];

    const int n = blockIdx.x;
    const int t0 = blockIdx.y * T_TILE;
    const int tid = threadIdx.x;

    if (tid < COUT) {
        float inv = gg[tid] * rsqrtf(vv[tid] + BNEPS);
        ssc[tid] = inv;
        ssh[tid] = bb[tid] - mm[tid] * inv;
    }

    // stage sx[t][ci0..ci0+7]: coalesced fp32 global reads (t fast), b128 LDS writes
    for (int uidx = tid; uidx < XT * (CIN / 8); uidx += 256) {
        int t = uidx % XT;
        int ci0 = (uidx / XT) * 8;
        int u = t0 - P + t;
        u = (u < 0) ? -u : u;
        u = (u >= LIN) ? (2 * (LIN - 1) - u) : u;
        const float* base = in + ((size_t)n * CIN + ci0) * LIN_BASE;
        short8v pack;
        if constexpr (UP_IN) {
            int i = u >> 1;
            int ia, ib; float wa, wbw;
            if (u & 1) { ia = i; ib = (i + 1 < LIN_BASE) ? i + 1 : LIN_BASE - 1; wa = 0.75f; wbw = 0.25f; }
            else if (i == 0) { ia = 0; ib = 0; wa = 1.0f; wbw = 0.0f; }
            else { ia = i - 1; ib = i; wa = 0.25f; wbw = 0.75f; }
#pragma unroll
            for (int j = 0; j < 8; ++j) {
                float v = wa * base[(size_t)j * LIN_BASE + ia] + wbw * base[(size_t)j * LIN_BASE + ib];
                __hip_bfloat16 h = __float2bfloat16(v);
                pack[j] = *(short*)&h;
            }
        } else {
#pragma unroll
            for (int j = 0; j < 8; ++j) {
                __hip_bfloat16 h = __float2bfloat16(base[(size_t)j * LIN_BASE + u]);
                pack[j] = *(short*)&h;
            }
        }
        *(short8v*)(sx + t * ROWW + ci0) = pack;
    }
    __syncthreads();

    const int wv = tid >> 6;
    const int lane = tid & 63;
    const int ln = lane & 15;     // A: m=co; B: n=t; D: col=t
    const int q = lane >> 4;      // k block (q*8..q*8+7)

    float4v acc[COT][TN];
#pragma unroll
    for (int c = 0; c < COT; ++c)
#pragma unroll
        for (int j = 0; j < TN; ++j)
            acc[c][j] = (float4v){0.f, 0.f, 0.f, 0.f};

    const short* sxb = sx + (wv * 64 + ln) * ROWW + q * 8;
    const short* wrow[COT];
#pragma unroll
    for (int c = 0; c < COT; ++c)
        wrow[c] = wb + (size_t)(c * 16 + ln) * K + q * 8;

#pragma unroll 1
    for (int tap = 0; tap < K5; ++tap) {
#pragma unroll
        for (int cb = 0; cb < CI32; ++cb) {
            const int koff = tap * CIN + cb * 32;
            short8v a[COT], b[TN];
#pragma unroll
            for (int c = 0; c < COT; ++c)
                a[c] = *(const short8v*)(wrow[c] + koff);
#pragma unroll
            for (int j = 0; j < TN; ++j)
                b[j] = *(const short8v*)(sxb + (tap * DIL + j * 16) * ROWW + cb * 32);
#pragma unroll
            for (int c = 0; c < COT; ++c)
#pragma unroll
                for (int j = 0; j < TN; ++j)
                    acc[c][j] = __builtin_amdgcn_mfma_f32_16x16x32_bf16(a[c], b[j], acc[c][j], 0, 0, 0);
        }
    }

    // epilogue: col(lane&15)=t (coalesced), row(q*4+r)=co
    float* ob = out + ((size_t)n * COUT) * LOUT + t0 + wv * 64 + ln;
#pragma unroll
    for (int c = 0; c < COT; ++c)
#pragma unroll
        for (int j = 0; j < TN; ++j) {
            float4v v = acc[c][j];
#pragma unroll
            for (int r = 0; r < 4; ++r) {
                int co = c * 16 + q * 4 + r;
                float val = fmaxf(v[r] * ssc[co] + ssh[co], 0.f);
                ob[(size_t)co * LOUT + j * 16] = val;
            }
        }
}

// ---------------- VALU conv (kept for COUT=8 / COUT=3 tail layers) -----------
template<int CIN, int COUT, int DIL, int LOUT, bool UP_IN, int THREADS_CO,
         int TT_T, int CI_CHUNK, bool HAS_BN>
__global__ __launch_bounds__(256) void conv_bn_up_ker(
    const float* __restrict__ in, const float* __restrict__ wgt,
    const float* __restrict__ gg, const float* __restrict__ bb,
    const float* __restrict__ mm, const float* __restrict__ vv,
    float* __restrict__ out)
{
    constexpr int THREADS = 256;
    constexpr int P = 2 * DIL;
    constexpr int THREADS_T = THREADS / THREADS_CO;
    constexpr int CO_T = COUT / THREADS_CO;
    constexpr int T_TILE = THREADS_T * TT_T;
    constexpr int XT = T_TILE + 4 * DIL;
    constexpr int W = TT_T + 4 * DIL;
    constexpr int LIN_BASE = UP_IN ? (LOUT / 2) : LOUT;
    constexpr int LIN = LOUT;

    __shared__ float sx[CI_CHUNK * XT];
    __shared__ float sw[CI_CHUNK * K5 * COUT];

    const int n = blockIdx.x;
    const int t0 = blockIdx.y * T_TILE;
    const int tid = threadIdx.x;
    const int co_grp = tid / THREADS_T;
    const int t_grp = tid % THREADS_T;
    const int co_base = co_grp * CO_T;

    float acc[CO_T * TT_T];
#pragma unroll
    for (int i = 0; i < CO_T * TT_T; ++i) acc[i] = 0.f;

    for (int ci0 = 0; ci0 < CIN; ci0 += CI_CHUNK) {
        if (ci0 != 0) __syncthreads();
        for (int idx = tid; idx < CI_CHUNK * K5 * COUT; idx += THREADS) {
            int co = idx % COUT;
            int r = idx / COUT;
            int ci = r / K5, k = r - ci * K5;
            sw[idx] = wgt[((size_t)co * CIN + (ci0 + ci)) * K5 + k];
        }
        for (int idx = tid; idx < CI_CHUNK * XT; idx += THREADS) {
            int ci = idx / XT;
            int j = idx - ci * XT;
            int u = t0 - P + j;
            u = (u < 0) ? -u : u;
            u = (u >= LIN) ? (2 * (LIN - 1) - u) : u;
            const float* base = in + ((size_t)n * CIN + (ci0 + ci)) * LIN_BASE;
            float val;
            if constexpr (UP_IN) {
                int i = u >> 1;
                if (u & 1) {
                    int i1 = (i + 1 < LIN_BASE) ? (i + 1) : (LIN_BASE - 1);
                    val = 0.75f * base[i] + 0.25f * base[i1];
                } else {
                    val = (i == 0) ? base[0] : (0.25f * base[i - 1] + 0.75f * base[i]);
                }
            } else {
                val = base[u];
            }
            sx[idx] = val;
        }
        __syncthreads();

#pragma unroll 1
        for (int ci = 0; ci < CI_CHUNK; ++ci) {
            float xw[W];
            const float4* xp = (const float4*)(sx + ci * XT + t_grp * TT_T);
#pragma unroll
            for (int j = 0; j < W / 4; ++j) {
                float4 v = xp[j];
                xw[4 * j + 0] = v.x; xw[4 * j + 1] = v.y;
                xw[4 * j + 2] = v.z; xw[4 * j + 3] = v.w;
            }
#pragma unroll
            for (int k = 0; k < K5; ++k) {
                float wv[CO_T];
#pragma unroll
                for (int a = 0; a < CO_T; ++a)
                    wv[a] = sw[(ci * K5 + k) * COUT + co_base + a];
#pragma unroll
                for (int a = 0; a < CO_T; ++a)
#pragma unroll
                    for (int b = 0; b < TT_T; ++b)
                        acc[a * TT_T + b] = fmaf(wv[a], xw[b + k * DIL], acc[a * TT_T + b]);
            }
        }
    }

#pragma unroll
    for (int a = 0; a < CO_T; ++a) {
        int co = co_base + a;
        float scale, shift;
        if constexpr (HAS_BN) {
            float inv = gg[co] / sqrtf(vv[co] + BNEPS);
            scale = inv;
            shift = bb[co] - mm[co] * inv;
        } else {
            scale = 1.f;
            shift = bb[co];
        }
        float* op = out + ((size_t)n * COUT + co) * LOUT + t0 + t_grp * TT_T;
#pragma unroll
        for (int qq = 0; qq < TT_T / 4; ++qq) {
            float r0 = acc[a * TT_T + 4 * qq + 0] * scale + shift;
            float r1 = acc[a * TT_T + 4 * qq + 1] * scale + shift;
            float r2 = acc[a * TT_T + 4 * qq + 2] * scale + shift;
            float r3 = acc[a * TT_T + 4 * qq + 3] * scale + shift;
            if constexpr (HAS_BN) {
                r0 = fmaxf(r0, 0.f); r1 = fmaxf(r1, 0.f);
                r2 = fmaxf(r2, 0.f); r3 = fmaxf(r3, 0.f);
            }
            float4 v; v.x = r0; v.y = r1; v.z = r2; v.w = r3;
            ((float4*)op)[qq] = v;
        }
    }
}

// ---------------- final upsample + transpose + loss --------------------------
__global__ __launch_bounds__(256) void up_loss_ker(
    const float* __restrict__ h4, const float* __restrict__ targets,
    float* __restrict__ out, float* __restrict__ loss_sum, int* __restrict__ flags)
{
    constexpr int L = 16384, LO = 32768;
    const int bt = blockIdx.x;
    const int t0 = blockIdx.y * 256;
    const int tid = threadIdx.x;
    const int st = tid & 7, tloc = tid >> 3;
    const int i0 = t0 >> 1;

    __shared__ float sh[3 * 8 * 132];
    __shared__ int snz[8];
    __shared__ float swv[4];

    for (int idx = tid; idx < 3 * 8 * 132; idx += 256) {
        int row = idx / 132;
        int j = idx - row * 132;
        int c = row >> 3, s = row & 7;
        int bi = i0 - 1 + j;
        bi = bi < 0 ? 0 : (bi > L - 1 ? L - 1 : bi);
        int n = bt * 8 + s;
        sh[idx] = h4[((size_t)n * 3 + c) * L + bi];
    }
    if (tid < 8) snz[tid] = 0;
    __syncthreads();

    float lsum = 0.f;
    int nz = 0;
#pragma unroll
    for (int r = 0; r < 8; ++r) {
        int t = t0 + r * 32 + tloc;
        float o[3], tg[3];
        int i = t >> 1;
        int li = i - i0 + 1;
#pragma unroll
        for (int c = 0; c < 3; ++c) {
            const float* row = sh + (c * 8 + st) * 132;
            float v;
            if (t & 1) v = 0.75f * row[li] + 0.25f * row[li + 1];
            else       v = 0.25f * row[li - 1] + 0.75f * row[li];
            o[c] = v;
            size_t oidx = (((size_t)bt * 3 + c) * LO + t) * 8 + st;
            out[oidx] = v;
            tg[c] = targets[oidx];
        }
        float mx = fmaxf(o[0], fmaxf(o[1], o[2]));
        float e0 = __expf(o[0] - mx), e1 = __expf(o[1] - mx), e2 = __expf(o[2] - mx);
        float lse = mx + __logf(e0 + e1 + e2);
        lsum += tg[0] * (lse - o[0]) + tg[1] * (lse - o[1]) + tg[2] * (lse - o[2]);
        nz |= (tg[0] != 0.f) | (tg[1] != 0.f) | (tg[2] != 0.f);
    }
    if (nz) snz[st] = 1;

#pragma unroll
    for (int off = 32; off > 0; off >>= 1) lsum += __shfl_down(lsum, off, 64);
    if ((tid & 63) == 0) swv[tid >> 6] = lsum;
    __syncthreads();
    if (tid == 0) atomicAdd(loss_sum, swv[0] + swv[1] + swv[2] + swv[3]);
    if (tid < 8 && snz[tid]) atomicOr(&flags[bt * 8 + tid], 1);
}

__global__ __launch_bounds__(256) void finalize_ker(
    const int* __restrict__ flags, const float* __restrict__ loss_sum,
    float* __restrict__ out_loss)
{
    __shared__ int s[256];
    s[threadIdx.x] = flags[threadIdx.x] ? 1 : 0;
    __syncthreads();
    for (int off = 128; off > 0; off >>= 1) {
        if (threadIdx.x < off) s[threadIdx.x] += s[threadIdx.x + off];
        __syncthreads();
    }
    if (threadIdx.x == 0) out_loss[0] = loss_sum[0] / ((float)s[0] * 32768.0f);
}

extern "C" void kernel_launch(void* const* d_in, const int* in_sizes, int n_in,
                              void* d_out, int out_size, void* d_ws, size_t ws_size,
                              hipStream_t stream)
{
    const float* x  = (const float*)d_in[0];
    const float* tg = (const float*)d_in[1];
    const float* w0 = (const float*)d_in[2];
    const float* g0 = (const float*)d_in[3];
    const float* b0 = (const float*)d_in[4];
    const float* m0 = (const float*)d_in[5];
    const float* v0 = (const float*)d_in[6];
    const float* w1 = (const float*)d_in[7];
    const float* g1 = (const float*)d_in[8];
    const float* b1 = (const float*)d_in[9];
    const float* m1 = (const float*)d_in[10];
    const float* v1 = (const float*)d_in[11];
    const float* w2 = (const float*)d_in[12];
    const float* g2 = (const float*)d_in[13];
    const float* b2 = (const float*)d_in[14];
    const float* m2 = (const float*)d_in[15];
    const float* v2 = (const float*)d_in[16];
    const float* w3 = (const float*)d_in[17];
    const float* g3 = (const float*)d_in[18];
    const float* b3 = (const float*)d_in[19];
    const float* m3 = (const float*)d_in[20];
    const float* v3 = (const float*)d_in[21];
    const float* w_out = (const float*)d_in[22];
    const float* b_out = (const float*)d_in[23];
    float* outp = (float*)d_out;

    char* ws = (char*)d_ws;
    int* flags = (int*)ws;                           // [0,1024)
    float* loss_sum = (float*)(ws + 1024);           // [1024,1028)
    short* wb0 = (short*)(ws + 4096);                // 64*640  bf16 = 81920 B
    short* wb1 = (short*)(ws + 4096 + 81920);        // 32*320  bf16 = 20480 B
    short* wb2 = (short*)(ws + 4096 + 102400);       // 16*160  bf16 =  5120 B
    const size_t BUF_OFF = 131072;
    const size_t BUFN = (size_t)16777216;            // floats per ping-pong buffer
    float* bufA = (float*)(ws + BUF_OFF);
    float* bufB = (ws_size >= BUF_OFF + 2 * BUFN * 4)
                      ? (bufA + BUFN)
                      : (float*)d_out;               // d_out as scratch fallback

    hipMemsetAsync(d_ws, 0, 4096, stream);

    wprep_ker<128, 64><<<(64 * 640 + 255) / 256, 256, 0, stream>>>(w0, wb0);
    wprep_ker<64, 32><<<(32 * 320 + 255) / 256, 256, 0, stream>>>(w1, wb1);
    wprep_ker<32, 16><<<(16 * 160 + 255) / 256, 256, 0, stream>>>(w2, wb2);

    // h0 (256,64,1024)  MFMA
    conv_mfma_ker<128, 64, 1, 1024, false>
        <<<dim3(256, 4), 256, 0, stream>>>(x, wb0, g0, b0, m0, v0, bufA);
    // h1 (256,32,2048)  MFMA
    conv_mfma_ker<64, 32, 2, 2048, true>
        <<<dim3(256, 8), 256, 0, stream>>>(bufA, wb1, g1, b1, m1, v1, bufB);
    // h2 (256,16,4096)  MFMA
    conv_mfma_ker<32, 16, 4, 4096, true>
        <<<dim3(256, 16), 256, 0, stream>>>(bufB, wb2, g2, b2, m2, v2, bufA);
    // h3 (256,8,8192)   VALU
    conv_bn_up_ker<16, 8, 8, 8192, true, 1, 8, 4, true>
        <<<dim3(256, 4), 256, 0, stream>>>(bufA, w3, g3, b3, m3, v3, bufB);
    // h4 (256,3,16384)  VALU
    conv_bn_up_ker<8, 3, 16, 16384, true, 1, 8, 4, false>
        <<<dim3(256, 8), 256, 0, stream>>>(bufB, w_out, b_out, b_out, b_out, b_out, bufA);
    // out + loss
    up_loss_ker<<<dim3(32, 128), 256, 0, stream>>>(bufA, tg, outp, loss_sum, flags);
    finalize_ker<<<1, 256, 0, stream>>>(flags, loss_sum, outp + (size_t)(out_size - 1));
}

// Round 3
// 594.943 us; speedup vs baseline: 1.9408x; 1.1381x over previous
//
#include <hip/hip_runtime.h>
#include <hip/hip_bf16.h>
#include <cstdint>
#include <cstddef>

#define K5 5
#define BNEPS 1e-5f

typedef __attribute__((ext_vector_type(8))) short short8v;
typedef __attribute__((ext_vector_type(4))) float float4v;

// ---- weight prep: fp32 [co][ci][tap] -> bf16 [co][kk], kk=tap*CIN+ci,
//      rows padded to MROWS (>=COUT) with zeros, k padded to KPAD with zeros.
template<int CIN, int COUT, int MROWS, int KPAD>
__global__ __launch_bounds__(256) void wprep2_ker(const float* __restrict__ w,
                                                  short* __restrict__ wb) {
    int idx = blockIdx.x * 256 + threadIdx.x;
    if (idx >= MROWS * KPAD) return;
    int co = idx / KPAD, kk = idx - co * KPAD;
    int tap = kk / CIN, ci = kk & (CIN - 1);
    float v = (co < COUT && tap < K5) ? w[((size_t)co * CIN + ci) * K5 + tap] : 0.f;
    __hip_bfloat16 h = __float2bfloat16(v);
    wb[idx] = *(short*)&h;
}

// ---- MFMA conv: (opt up2 of input) -> reflect-pad dilated conv -> BN+ReLU|bias
// GEMM D[co][t] = W[co][kk] * X[kk][t], kk = tap*CIN+ci.
// X staged once in LDS as sx[t][ci] bf16 (row stride CIN+8), no barrier in
// K-loop; weights streamed from pre-transposed bf16 global with 1-step prefetch.
// Wave split: WT wave-groups along t (TN t-tiles each), each wave does all
// WCOT co-tiles (B-frags reused across co -> few LDS reads per K-step).
template<int CIN, int COUT, int DIL, int LOUT, bool UP_IN, int T_TILE, int WT,
         bool HAS_BN>
__global__ __launch_bounds__(256) void conv_mfma2_ker(
    const float* __restrict__ in, const short* __restrict__ wb,
    const float* __restrict__ gg, const float* __restrict__ bb,
    const float* __restrict__ mm, const float* __restrict__ vv,
    float* __restrict__ out)
{
    constexpr int P = 2 * DIL;                  // ((K-1)*d+1)//2 == 2d
    constexpr int XT = T_TILE + 4 * DIL;
    constexpr int ROWW = CIN + 8;               // shorts; multiple of 8 -> 16B rows
    constexpr int K = CIN * K5;
    constexpr int KPAD = ((K + 31) / 32) * 32;
    constexpr int NSTEP = KPAD / 32;
    constexpr int MT = (COUT + 15) / 16;        // co tiles (zero-padded rows)
    constexpr int WCOT = MT;                    // co-tiles per wave (WCO=1)
    constexpr int TN = T_TILE / (16 * WT);      // t-tiles per wave
    constexpr int LIN = LOUT;
    constexpr int LIN_BASE = UP_IN ? (LOUT / 2) : LOUT;

    __shared__ short sx[XT * ROWW];
    __shared__ float ssc[COUT], ssh[COUT];

    const int n = blockIdx.x;
    const int t0 = blockIdx.y * T_TILE;
    const int tid = threadIdx.x;

    if (tid < COUT) {
        if constexpr (HAS_BN) {
            float inv = gg[tid] * rsqrtf(vv[tid] + BNEPS);
            ssc[tid] = inv;
            ssh[tid] = bb[tid] - mm[tid] * inv;
        } else {
            ssc[tid] = 1.f;
            ssh[tid] = bb[tid];
        }
    }

    // stage sx[t][ci0..ci0+7]: coalesced fp32 global reads, b128 LDS writes
    for (int uidx = tid; uidx < XT * (CIN / 8); uidx += 256) {
        int t = uidx % XT;
        int ci0 = (uidx / XT) * 8;
        int u = t0 - P + t;
        u = (u < 0) ? -u : u;
        u = (u >= LIN) ? (2 * (LIN - 1) - u) : u;
        const float* base = in + ((size_t)n * CIN + ci0) * LIN_BASE;
        short8v pack;
        if constexpr (UP_IN) {
            int i = u >> 1;
            int ia, ib; float wa, wbw;
            if (u & 1) { ia = i; ib = (i + 1 < LIN_BASE) ? i + 1 : LIN_BASE - 1; wa = 0.75f; wbw = 0.25f; }
            else if (i == 0) { ia = 0; ib = 0; wa = 1.0f; wbw = 0.0f; }
            else { ia = i - 1; ib = i; wa = 0.25f; wbw = 0.75f; }
#pragma unroll
            for (int j = 0; j < 8; ++j) {
                float v = wa * base[(size_t)j * LIN_BASE + ia] + wbw * base[(size_t)j * LIN_BASE + ib];
                __hip_bfloat16 h = __float2bfloat16(v);
                pack[j] = *(short*)&h;
            }
        } else {
#pragma unroll
            for (int j = 0; j < 8; ++j) {
                __hip_bfloat16 h = __float2bfloat16(base[(size_t)j * LIN_BASE + u]);
                pack[j] = *(short*)&h;
            }
        }
        *(short8v*)(sx + t * ROWW + ci0) = pack;
    }
    __syncthreads();

    const int wvi = tid >> 6;
    const int lane = tid & 63;
    const int ln = lane & 15;     // A: m=co row; B: n=t; D: col=t
    const int q = lane >> 4;      // k sub-block (q*8..q*8+7)
    const int tw = wvi * (TN * 16);

    float4v acc[WCOT][TN];
#pragma unroll
    for (int c = 0; c < WCOT; ++c)
#pragma unroll
        for (int j = 0; j < TN; ++j)
            acc[c][j] = (float4v){0.f, 0.f, 0.f, 0.f};

    const short* arow[WCOT];
#pragma unroll
    for (int c = 0; c < WCOT; ++c)
        arow[c] = wb + ((size_t)(c * 16 + ln)) * KPAD + q * 8;

    short8v acur[WCOT], anx[WCOT];
#pragma unroll
    for (int c = 0; c < WCOT; ++c)
        acur[c] = *(const short8v*)(arow[c]);

#pragma unroll 1
    for (int s = 0; s < NSTEP; ++s) {
        if (s + 1 < NSTEP) {
#pragma unroll
            for (int c = 0; c < WCOT; ++c)
                anx[c] = *(const short8v*)(arow[c] + (s + 1) * 32);
        }
        const int kk = s * 32 + q * 8;
        int tap = kk / CIN;                    // pow2 -> shift
        const int ci0 = kk & (CIN - 1);
        if constexpr (KPAD != K) {
            tap = (tap < K5) ? tap : (K5 - 1); // clamp addr for padded region
        }
        short8v b[TN];
#pragma unroll
        for (int j = 0; j < TN; ++j)
            b[j] = *(const short8v*)(sx + (tw + j * 16 + ln + tap * DIL) * ROWW + ci0);
        if constexpr (KPAD != K) {
            if (kk >= K) {
                short8v z = {0, 0, 0, 0, 0, 0, 0, 0};
#pragma unroll
                for (int j = 0; j < TN; ++j) b[j] = z;
            }
        }
#pragma unroll
        for (int c = 0; c < WCOT; ++c)
#pragma unroll
            for (int j = 0; j < TN; ++j)
                acc[c][j] = __builtin_amdgcn_mfma_f32_16x16x32_bf16(acur[c], b[j], acc[c][j], 0, 0, 0);
#pragma unroll
        for (int c = 0; c < WCOT; ++c)
            acur[c] = anx[c];
    }

    // epilogue: D col(ln)=t (coalesced), row(q*4+r)=co
    float* ob = out + (size_t)n * COUT * LOUT + t0 + tw + ln;
#pragma unroll
    for (int c = 0; c < WCOT; ++c)
#pragma unroll
        for (int j = 0; j < TN; ++j) {
            float4v v = acc[c][j];
#pragma unroll
            for (int r = 0; r < 4; ++r) {
                int co = c * 16 + q * 4 + r;
                if ((COUT % 16 == 0) || co < COUT) {
                    float val = v[r] * ssc[co] + ssh[co];
                    if constexpr (HAS_BN) val = fmaxf(val, 0.f);
                    ob[(size_t)co * LOUT + j * 16] = val;
                }
            }
        }
}

// ---- final upsample + transpose + loss --------------------------------------
__global__ __launch_bounds__(256) void up_loss_ker(
    const float* __restrict__ h4, const float* __restrict__ targets,
    float* __restrict__ out, float* __restrict__ loss_sum, int* __restrict__ flags)
{
    constexpr int L = 16384, LO = 32768;
    const int bt = blockIdx.x;
    const int t0 = blockIdx.y * 256;
    const int tid = threadIdx.x;
    const int st = tid & 7, tloc = tid >> 3;
    const int i0 = t0 >> 1;

    __shared__ float sh[3 * 8 * 132];
    __shared__ int snz[8];
    __shared__ float swv[4];

    for (int idx = tid; idx < 3 * 8 * 132; idx += 256) {
        int row = idx / 132;
        int j = idx - row * 132;
        int c = row >> 3, s = row & 7;
        int bi = i0 - 1 + j;
        bi = bi < 0 ? 0 : (bi > L - 1 ? L - 1 : bi);
        int n = bt * 8 + s;
        sh[idx] = h4[((size_t)n * 3 + c) * L + bi];
    }
    if (tid < 8) snz[tid] = 0;
    __syncthreads();

    float lsum = 0.f;
    int nz = 0;
#pragma unroll
    for (int r = 0; r < 8; ++r) {
        int t = t0 + r * 32 + tloc;
        float o[3], tg[3];
        int i = t >> 1;
        int li = i - i0 + 1;
#pragma unroll
        for (int c = 0; c < 3; ++c) {
            const float* row = sh + (c * 8 + st) * 132;
            float v;
            if (t & 1) v = 0.75f * row[li] + 0.25f * row[li + 1];
            else       v = 0.25f * row[li - 1] + 0.75f * row[li];
            o[c] = v;
            size_t oidx = (((size_t)bt * 3 + c) * LO + t) * 8 + st;
            out[oidx] = v;
            tg[c] = targets[oidx];
        }
        float mx = fmaxf(o[0], fmaxf(o[1], o[2]));
        float e0 = __expf(o[0] - mx), e1 = __expf(o[1] - mx), e2 = __expf(o[2] - mx);
        float lse = mx + __logf(e0 + e1 + e2);
        lsum += tg[0] * (lse - o[0]) + tg[1] * (lse - o[1]) + tg[2] * (lse - o[2]);
        nz |= (tg[0] != 0.f) | (tg[1] != 0.f) | (tg[2] != 0.f);
    }
    if (nz) snz[st] = 1;

#pragma unroll
    for (int off = 32; off > 0; off >>= 1) lsum += __shfl_down(lsum, off, 64);
    if ((tid & 63) == 0) swv[tid >> 6] = lsum;
    __syncthreads();
    if (tid == 0) atomicAdd(loss_sum, swv[0] + swv[1] + swv[2] + swv[3]);
    if (tid < 8 && snz[tid]) atomicOr(&flags[bt * 8 + tid], 1);
}

__global__ __launch_bounds__(256) void finalize_ker(
    const int* __restrict__ flags, const float* __restrict__ loss_sum,
    float* __restrict__ out_loss)
{
    __shared__ int s[256];
    s[threadIdx.x] = flags[threadIdx.x] ? 1 : 0;
    __syncthreads();
    for (int off = 128; off > 0; off >>= 1) {
        if (threadIdx.x < off) s[threadIdx.x] += s[threadIdx.x + off];
        __syncthreads();
    }
    if (threadIdx.x == 0) out_loss[0] = loss_sum[0] / ((float)s[0] * 32768.0f);
}

extern "C" void kernel_launch(void* const* d_in, const int* in_sizes, int n_in,
                              void* d_out, int out_size, void* d_ws, size_t ws_size,
                              hipStream_t stream)
{
    const float* x  = (const float*)d_in[0];
    const float* tg = (const float*)d_in[1];
    const float* w0 = (const float*)d_in[2];
    const float* g0 = (const float*)d_in[3];
    const float* b0 = (const float*)d_in[4];
    const float* m0 = (const float*)d_in[5];
    const float* v0 = (const float*)d_in[6];
    const float* w1 = (const float*)d_in[7];
    const float* g1 = (const float*)d_in[8];
    const float* b1 = (const float*)d_in[9];
    const float* m1 = (const float*)d_in[10];
    const float* v1 = (const float*)d_in[11];
    const float* w2 = (const float*)d_in[12];
    const float* g2 = (const float*)d_in[13];
    const float* b2 = (const float*)d_in[14];
    const float* m2 = (const float*)d_in[15];
    const float* v2 = (const float*)d_in[16];
    const float* w3 = (const float*)d_in[17];
    const float* g3 = (const float*)d_in[18];
    const float* b3 = (const float*)d_in[19];
    const float* m3 = (const float*)d_in[20];
    const float* v3 = (const float*)d_in[21];
    const float* w_out = (const float*)d_in[22];
    const float* b_out = (const float*)d_in[23];
    float* outp = (float*)d_out;

    char* ws = (char*)d_ws;
    int* flags = (int*)ws;                           // [0,1024)
    float* loss_sum = (float*)(ws + 1024);
    short* wb0 = (short*)(ws + 4096);                // 64 x 640  = 81920 B
    short* wb1 = (short*)(ws + 86016);               // 32 x 320  = 20480 B
    short* wb2 = (short*)(ws + 106496);              // 16 x 160  =  5120 B
    short* wb3 = (short*)(ws + 111616);              // 16 x 96   =  3072 B
    short* wb4 = (short*)(ws + 114688);              // 16 x 64   =  2048 B
    const size_t BUF_OFF = 131072;
    const size_t BUFN = (size_t)16777216;            // floats per ping-pong buffer
    float* bufA = (float*)(ws + BUF_OFF);
    float* bufB = (ws_size >= BUF_OFF + 2 * BUFN * 4)
                      ? (bufA + BUFN)
                      : (float*)d_out;               // d_out as scratch fallback

    hipMemsetAsync(d_ws, 0, 4096, stream);

    wprep2_ker<128, 64, 64, 640><<<160, 256, 0, stream>>>(w0, wb0);
    wprep2_ker<64, 32, 32, 320><<<40, 256, 0, stream>>>(w1, wb1);
    wprep2_ker<32, 16, 16, 160><<<10, 256, 0, stream>>>(w2, wb2);
    wprep2_ker<16, 8, 16, 96><<<6, 256, 0, stream>>>(w3, wb3);
    wprep2_ker<8, 3, 16, 64><<<4, 256, 0, stream>>>(w_out, wb4);

    // h0 (256,64,1024)   T_TILE=128, 36KB LDS, WCOT=4, TN=2
    conv_mfma2_ker<128, 64, 1, 1024, false, 128, 4, true>
        <<<dim3(256, 8), 256, 0, stream>>>(x, wb0, g0, b0, m0, v0, bufA);
    // h1 (256,32,2048)   T_TILE=128, 20KB LDS, WCOT=2, TN=2
    conv_mfma2_ker<64, 32, 2, 2048, true, 128, 4, true>
        <<<dim3(256, 16), 256, 0, stream>>>(bufA, wb1, g1, b1, m1, v1, bufB);
    // h2 (256,16,4096)   T_TILE=256, 22KB LDS, WCOT=1, TN=4
    conv_mfma2_ker<32, 16, 4, 4096, true, 256, 4, true>
        <<<dim3(256, 16), 256, 0, stream>>>(bufB, wb2, g2, b2, m2, v2, bufA);
    // h3 (256,8,8192)    T_TILE=256, 14KB LDS, WCOT=1, TN=4
    conv_mfma2_ker<16, 8, 8, 8192, true, 256, 4, true>
        <<<dim3(256, 32), 256, 0, stream>>>(bufA, wb3, g3, b3, m3, v3, bufB);
    // h4 (256,3,16384)   T_TILE=256, 10KB LDS, WCOT=1, TN=4
    conv_mfma2_ker<8, 3, 16, 16384, true, 256, 4, false>
        <<<dim3(256, 64), 256, 0, stream>>>(bufB, wb4, b_out, b_out, b_out, b_out, bufA);
    // out + loss
    up_loss_ker<<<dim3(32, 128), 256, 0, stream>>>(bufA, tg, outp, loss_sum, flags);
    finalize_ker<<<1, 256, 0, stream>>>(flags, loss_sum, outp + (size_t)(out_size - 1));
}